// Round 1
// baseline (1010.843 us; speedup 1.0000x reference)
//
#include <hip/hip_runtime.h>

typedef _Float16 half_t;
typedef __attribute__((ext_vector_type(8))) _Float16 half8;
typedef __attribute__((ext_vector_type(2))) _Float16 half2v;
typedef __attribute__((ext_vector_type(4))) float floatx4;

#define BM 128
#define BN 128
#define BK 32

// ---------------- conversion: x fp32 -> fp16 ----------------
__global__ void cvt_x_kernel(const float* __restrict__ in, half_t* __restrict__ out, long n) {
    long i = ((long)blockIdx.x * blockDim.x + threadIdx.x) * 8;
    if (i >= n) return;
    const floatx4* p = (const floatx4*)(in + i);
    floatx4 a = p[0], b = p[1];
    half8 h;
    h[0] = (half_t)a[0]; h[1] = (half_t)a[1]; h[2] = (half_t)a[2]; h[3] = (half_t)a[3];
    h[4] = (half_t)b[0]; h[5] = (half_t)b[1]; h[6] = (half_t)b[2]; h[7] = (half_t)b[3];
    *(half8*)(out + i) = h;
}

// ---------------- conversion + transpose: W[k][n] -> Wt[n][k] fp16 ----------------
__global__ void cvt_w_kernel(const float* __restrict__ W, half_t* __restrict__ Wt, int K, int NN) {
    int idx = blockIdx.x * blockDim.x + threadIdx.x;
    if (idx >= K * NN) return;
    int nn = idx / K;
    int kk = idx - nn * K;
    Wt[idx] = (half_t)W[(long)kk * NN + nn];   // coalesced store, strided load (W is 3 MB, L2-resident)
}

// ---------------- GEMM: H[M][NN] = A[M][K] * Bt[NN][K]^T  (m97-style) ----------------
__global__ __launch_bounds__(256) void gemm_kernel(
    const half_t* __restrict__ A,    // [M][K] row-major, K=512
    const half_t* __restrict__ Bt,   // [NN][K] row-major (B transposed)
    half_t* __restrict__ H,          // [M][NN]
    int M, int K, int NN)
{
    __shared__ half_t As[BM * BK];   // [m][k], 32 halves (64 B) per row
    __shared__ half_t Bs[BN * BK];   // [n][k]

    const int t    = threadIdx.x;        // 0..255 (4 waves)
    const int lane = t & 63;
    const int wave = t >> 6;
    const int wm   = (wave >> 1) * 64;   // wave's 64x64 quadrant
    const int wn   = (wave & 1) * 64;
    const int m0   = blockIdx.y * BM;
    const int n0   = blockIdx.x * BN;

    // staging: segment s (0..511) = row s>>2, k-octet s&3; LDS dest = s*16 bytes
    // -> exactly wave-uniform base + lane*16, and exactly row-major [128][32]
    const int r1 = t >> 2;
    const int r2 = (t + 256) >> 2;
    const int k8 = (t & 3) * 8;
    const long gA1 = (long)min(m0 + r1, M - 1) * K + k8;   // clamp: tail block reads row M-1
    const long gA2 = (long)min(m0 + r2, M - 1) * K + k8;
    const long gB1 = (long)(n0 + r1) * K + k8;             // NN=1536 divisible by 128, no clamp
    const long gB2 = (long)(n0 + r2) * K + k8;

    floatx4 acc[4][4] = {};

    const int mrow = wm + (lane & 15);
    const int nrow = wn + (lane & 15);
    const int koff = (lane >> 4) * 8;    // A[m][k]: k = (lane>>4)*8 + j  (verified layout)

    for (int kt = 0; kt < K; kt += BK) {
        __builtin_amdgcn_global_load_lds(
            (const __attribute__((address_space(1))) void*)(A + gA1 + kt),
            (__attribute__((address_space(3))) void*)(As + t * 8), 16, 0, 0);
        __builtin_amdgcn_global_load_lds(
            (const __attribute__((address_space(1))) void*)(A + gA2 + kt),
            (__attribute__((address_space(3))) void*)(As + (t + 256) * 8), 16, 0, 0);
        __builtin_amdgcn_global_load_lds(
            (const __attribute__((address_space(1))) void*)(Bt + gB1 + kt),
            (__attribute__((address_space(3))) void*)(Bs + t * 8), 16, 0, 0);
        __builtin_amdgcn_global_load_lds(
            (const __attribute__((address_space(1))) void*)(Bt + gB2 + kt),
            (__attribute__((address_space(3))) void*)(Bs + (t + 256) * 8), 16, 0, 0);
        __syncthreads();   // compiler emits vmcnt(0) drain before s_barrier

        half8 af[4], bf[4];
#pragma unroll
        for (int i = 0; i < 4; ++i)
            af[i] = *(const half8*)&As[(mrow + i * 16) * BK + koff];
#pragma unroll
        for (int i = 0; i < 4; ++i)
            bf[i] = *(const half8*)&Bs[(nrow + i * 16) * BK + koff];
#pragma unroll
        for (int i = 0; i < 4; ++i)
#pragma unroll
            for (int j = 0; j < 4; ++j)
                acc[i][j] = __builtin_amdgcn_mfma_f32_16x16x32_f16(af[i], bf[j], acc[i][j], 0, 0, 0);
        __syncthreads();
    }

    // epilogue: D[m][n]: col = lane&15, row = (lane>>4)*4 + reg  (verified m89/m91)
    const int col0 = lane & 15;
    const int rbase = (lane >> 4) * 4;
#pragma unroll
    for (int i = 0; i < 4; ++i) {
#pragma unroll
        for (int r = 0; r < 4; ++r) {
            int row = m0 + wm + i * 16 + rbase + r;
            if (row >= M) continue;
            long base = (long)row * NN + n0 + wn + col0;
#pragma unroll
            for (int j = 0; j < 4; ++j)
                H[base + j * 16] = (half_t)acc[i][j][r];
        }
    }
}

// ---------------- edge kernel: out[dst] += sum_s eta[e,s] * h[src, s, :] ----------------
__global__ void edge_kernel(const half_t* __restrict__ H,
                            const float* __restrict__ eta,
                            const int* __restrict__ src,
                            const int* __restrict__ dst,
                            float* __restrict__ out,
                            int C3, int C)
{
    const int e  = blockIdx.x;
    const int s  = src[e];
    const int d  = dst[e];
    const float e0 = eta[e * 3 + 0];
    const float e1 = eta[e * 3 + 1];
    const float e2 = eta[e * 3 + 2];
    const half_t* hrow = H + (long)s * C3;
    float* orow = out + (long)d * C;
    const int c = threadIdx.x * 2;   // 256 threads x 2 channels
    half2v h0 = *(const half2v*)&hrow[c];
    half2v h1 = *(const half2v*)&hrow[C + c];
    half2v h2 = *(const half2v*)&hrow[2 * C + c];
    float v0 = e0 * (float)h0[0] + e1 * (float)h1[0] + e2 * (float)h2[0];
    float v1 = e0 * (float)h0[1] + e1 * (float)h1[1] + e2 * (float)h2[1];
    atomicAdd(&orow[c], v0);
    atomicAdd(&orow[c + 1], v1);
}

// ---------------- finalize: out = tanh(out + bias[c]) in-place ----------------
__global__ void finalize_kernel(float* __restrict__ out, const float* __restrict__ bias,
                                long total, int Cmask)
{
    long i = ((long)blockIdx.x * blockDim.x + threadIdx.x) * 4;
    if (i >= total) return;
    floatx4 v = *(floatx4*)(out + i);
    int c = (int)(i & (long)Cmask);
#pragma unroll
    for (int j = 0; j < 4; ++j) {
        float x = v[j] + bias[c + j];
        float ex = __expf(2.0f * x);         // v_exp_f32 path; inf/0 saturate to +/-1 correctly
        v[j] = 1.0f - 2.0f / (ex + 1.0f);
    }
    *(floatx4*)(out + i) = v;
}

extern "C" void kernel_launch(void* const* d_in, const int* in_sizes, int n_in,
                              void* d_out, int out_size, void* d_ws, size_t ws_size,
                              hipStream_t stream) {
    const float* x    = (const float*)d_in[0];
    const float* W    = (const float*)d_in[1];
    const float* bias = (const float*)d_in[2];
    const float* eta  = (const float*)d_in[3];
    const int*   src  = (const int*)d_in[4];
    const int*   dst  = (const int*)d_in[5];
    float* out = (float*)d_out;

    const int  C   = in_sizes[2];          // 512
    const int  C3  = 3 * C;                // 1536
    const int  D   = in_sizes[1] / C3;     // 512
    const long xcount = in_sizes[0];       // N*D
    const int  N   = (int)(xcount / D);    // 100000
    const int  E   = in_sizes[4];          // 100000

    // workspace layout (all 16B-aligned offsets): x_h | Wt_h | H  (~411 MB)
    char* ws = (char*)d_ws;
    half_t* x_h  = (half_t*)ws;
    half_t* Wt_h = (half_t*)(ws + (size_t)N * D * sizeof(half_t));
    half_t* H    = (half_t*)(ws + (size_t)N * D * sizeof(half_t)
                                + (size_t)C3 * D * sizeof(half_t));

    // 1. x -> fp16
    {
        long nblk = (xcount / 8 + 255) / 256;
        cvt_x_kernel<<<dim3((unsigned)nblk), 256, 0, stream>>>(x, x_h, xcount);
    }
    // 2. W -> fp16, transposed to [3C][D]
    {
        int total = D * C3;
        cvt_w_kernel<<<(total + 255) / 256, 256, 0, stream>>>(W, Wt_h, D, C3);
    }
    // 3. zero the accumulator (= d_out; harness poisons it each call)
    hipMemsetAsync(out, 0, (size_t)out_size * sizeof(float), stream);
    // 4. GEMM h = x @ W
    {
        dim3 grid(C3 / BN, (N + BM - 1) / BM);   // x fastest over n-blocks for A-tile L2 reuse
        gemm_kernel<<<grid, 256, 0, stream>>>(x_h, Wt_h, H, N, D, C3);
    }
    // 5. edge gather/scale/scatter
    edge_kernel<<<E, C / 2, 0, stream>>>(H, eta, src, dst, out, C3, C);
    // 6. bias + tanh
    {
        long total = (long)N * C;
        finalize_kernel<<<(unsigned)((total / 4 + 255) / 256), 256, 0, stream>>>(out, bias, total, C - 1);
    }
}

// Round 2
// 722.237 us; speedup vs baseline: 1.3996x; 1.3996x over previous
//
#include <hip/hip_runtime.h>

typedef _Float16 half_t;
typedef __attribute__((ext_vector_type(8))) _Float16 half8;
typedef __attribute__((ext_vector_type(4))) float floatx4;

#define BM 128
#define BN 128
#define BK 32

// ---------------- conversion: x fp32 -> fp16 ----------------
__global__ void cvt_x_kernel(const float* __restrict__ in, half_t* __restrict__ out, long n) {
    long i = ((long)blockIdx.x * blockDim.x + threadIdx.x) * 8;
    if (i >= n) return;
    const floatx4* p = (const floatx4*)(in + i);
    floatx4 a = p[0], b = p[1];
    half8 h;
    h[0] = (half_t)a[0]; h[1] = (half_t)a[1]; h[2] = (half_t)a[2]; h[3] = (half_t)a[3];
    h[4] = (half_t)b[0]; h[5] = (half_t)b[1]; h[6] = (half_t)b[2]; h[7] = (half_t)b[3];
    *(half8*)(out + i) = h;
}

// ---------------- conversion + transpose: W[k][n] -> Wt[n][k] fp16 ----------------
__global__ void cvt_w_kernel(const float* __restrict__ W, half_t* __restrict__ Wt, int K, int NN) {
    int idx = blockIdx.x * blockDim.x + threadIdx.x;
    if (idx >= K * NN) return;
    int nn = idx / K;
    int kk = idx - nn * K;
    Wt[idx] = (half_t)W[(long)kk * NN + nn];   // coalesced store; W is 3 MB, L2-resident
}

// ---------------- GEMM: H[M][NN] = A[M][K] * Bt[NN][K]^T  (m97-style) ----------------
__global__ __launch_bounds__(256) void gemm_kernel(
    const half_t* __restrict__ A,    // [M][K] row-major, K=512
    const half_t* __restrict__ Bt,   // [NN][K] row-major (B transposed)
    half_t* __restrict__ H,          // [M][NN]
    int M, int K, int NN)
{
    __shared__ half_t As[BM * BK];
    __shared__ half_t Bs[BN * BK];

    const int t    = threadIdx.x;
    const int lane = t & 63;
    const int wave = t >> 6;
    const int wm   = (wave >> 1) * 64;
    const int wn   = (wave & 1) * 64;
    const int m0   = blockIdx.y * BM;
    const int n0   = blockIdx.x * BN;

    const int r1 = t >> 2;
    const int r2 = (t + 256) >> 2;
    const int k8 = (t & 3) * 8;
    const long gA1 = (long)min(m0 + r1, M - 1) * K + k8;
    const long gA2 = (long)min(m0 + r2, M - 1) * K + k8;
    const long gB1 = (long)(n0 + r1) * K + k8;
    const long gB2 = (long)(n0 + r2) * K + k8;

    floatx4 acc[4][4] = {};

    const int mrow = wm + (lane & 15);
    const int nrow = wn + (lane & 15);
    const int koff = (lane >> 4) * 8;

    for (int kt = 0; kt < K; kt += BK) {
        __builtin_amdgcn_global_load_lds(
            (const __attribute__((address_space(1))) void*)(A + gA1 + kt),
            (__attribute__((address_space(3))) void*)(As + t * 8), 16, 0, 0);
        __builtin_amdgcn_global_load_lds(
            (const __attribute__((address_space(1))) void*)(A + gA2 + kt),
            (__attribute__((address_space(3))) void*)(As + (t + 256) * 8), 16, 0, 0);
        __builtin_amdgcn_global_load_lds(
            (const __attribute__((address_space(1))) void*)(Bt + gB1 + kt),
            (__attribute__((address_space(3))) void*)(Bs + t * 8), 16, 0, 0);
        __builtin_amdgcn_global_load_lds(
            (const __attribute__((address_space(1))) void*)(Bt + gB2 + kt),
            (__attribute__((address_space(3))) void*)(Bs + (t + 256) * 8), 16, 0, 0);
        __syncthreads();

        half8 af[4], bf[4];
#pragma unroll
        for (int i = 0; i < 4; ++i)
            af[i] = *(const half8*)&As[(mrow + i * 16) * BK + koff];
#pragma unroll
        for (int i = 0; i < 4; ++i)
            bf[i] = *(const half8*)&Bs[(nrow + i * 16) * BK + koff];
#pragma unroll
        for (int i = 0; i < 4; ++i)
#pragma unroll
            for (int j = 0; j < 4; ++j)
                acc[i][j] = __builtin_amdgcn_mfma_f32_16x16x32_f16(af[i], bf[j], acc[i][j], 0, 0, 0);
        __syncthreads();
    }

    const int col0 = lane & 15;
    const int rbase = (lane >> 4) * 4;
#pragma unroll
    for (int i = 0; i < 4; ++i) {
#pragma unroll
        for (int r = 0; r < 4; ++r) {
            int row = m0 + wm + i * 16 + rbase + r;
            if (row >= M) continue;
            long base = (long)row * NN + n0 + wn + col0;
#pragma unroll
            for (int j = 0; j < 4; ++j)
                H[base + j * 16] = (half_t)acc[i][j][r];
        }
    }
}

// ---------------- counting sort of edges by dst ----------------
__global__ void hist_kernel(const int* __restrict__ dst, int* __restrict__ deg, int E) {
    int e = blockIdx.x * blockDim.x + threadIdx.x;
    if (e < E) atomicAdd(&deg[dst[e]], 1);
}

// per-1024-chunk sums (256 threads x 4 elems)
__global__ void scan_partial_kernel(const int* __restrict__ deg, int* __restrict__ bsum, int n) {
    __shared__ int wsum[4];
    int t = threadIdx.x, lane = t & 63, w = t >> 6;
    int base = blockIdx.x * 1024 + t * 4;
    int s = 0;
#pragma unroll
    for (int j = 0; j < 4; ++j) { int i = base + j; if (i < n) s += deg[i]; }
#pragma unroll
    for (int o = 1; o < 64; o <<= 1) s += __shfl_xor(s, o);
    if (lane == 0) wsum[w] = s;
    __syncthreads();
    if (t == 0) bsum[blockIdx.x] = wsum[0] + wsum[1] + wsum[2] + wsum[3];
}

// exclusive scan of the (tiny) block-sum array, single thread
__global__ void scan_bsums_kernel(int* __restrict__ bsum, int nb) {
    int acc = 0;
    for (int i = 0; i < nb; ++i) { int v = bsum[i]; bsum[i] = acc; acc += v; }
}

// final: off[i] = exclusive prefix of deg
__global__ void scan_final_kernel(const int* __restrict__ deg, const int* __restrict__ bsum,
                                  int* __restrict__ off, int n) {
    __shared__ int wsum[4];
    int t = threadIdx.x, lane = t & 63, w = t >> 6;
    int base = blockIdx.x * 1024 + t * 4;
    int v[4]; int s = 0;
#pragma unroll
    for (int j = 0; j < 4; ++j) { int i = base + j; v[j] = (i < n) ? deg[i] : 0; s += v[j]; }
    int sc = s;
#pragma unroll
    for (int o = 1; o < 64; o <<= 1) { int u = __shfl_up(sc, o); if (lane >= o) sc += u; }
    if (lane == 63) wsum[w] = sc;
    __syncthreads();
    int woff = 0;
    for (int i = 0; i < w; ++i) woff += wsum[i];
    int ex = bsum[blockIdx.x] + woff + (sc - s);
#pragma unroll
    for (int j = 0; j < 4; ++j) { int i = base + j; if (i < n) off[i] = ex; ex += v[j]; }
}

__global__ void scatter_kernel(const int* __restrict__ dst, const int* __restrict__ off,
                               int* __restrict__ cursor, int* __restrict__ eidx, int E) {
    int e = blockIdx.x * blockDim.x + threadIdx.x;
    if (e >= E) return;
    int d = dst[e];
    int p = off[d] + atomicAdd(&cursor[d], 1);
    eidx[p] = e;
}

// ---------------- aggregation: one wave per node, fused bias+tanh ----------------
__global__ __launch_bounds__(256) void agg_kernel(
    const half_t* __restrict__ H, const float* __restrict__ eta,
    const int* __restrict__ src, const int* __restrict__ off,
    const int* __restrict__ deg, const int* __restrict__ eidx,
    const float* __restrict__ bias, float* __restrict__ out,
    int N, int C, int C3)
{
    int node = blockIdx.x * 4 + (threadIdx.x >> 6);
    if (node >= N) return;
    int lane = threadIdx.x & 63;

    float acc[8] = {0.f, 0.f, 0.f, 0.f, 0.f, 0.f, 0.f, 0.f};
    int start = off[node];
    int d = deg[node];
    for (int q = 0; q < d; ++q) {
        int e = eidx[start + q];
        int s = src[e];
        float e0 = eta[3 * e + 0], e1 = eta[3 * e + 1], e2 = eta[3 * e + 2];
        const half_t* hrow = H + (long)s * C3 + lane * 8;
        half8 h0 = *(const half8*)hrow;
        half8 h1 = *(const half8*)(hrow + C);
        half8 h2 = *(const half8*)(hrow + 2 * C);
#pragma unroll
        for (int j = 0; j < 8; ++j)
            acc[j] += e0 * (float)h0[j] + e1 * (float)h1[j] + e2 * (float)h2[j];
    }
    const float* bp = bias + lane * 8;
    floatx4 o0, o1;
#pragma unroll
    for (int j = 0; j < 8; ++j) {
        float x = acc[j] + bp[j];
        float ex = __expf(2.0f * x);
        float r = 1.0f - 2.0f / (ex + 1.0f);
        if (j < 4) o0[j] = r; else o1[j - 4] = r;
    }
    float* op = out + (long)node * C + lane * 8;
    *(floatx4*)op = o0;
    *(floatx4*)(op + 4) = o1;
}

extern "C" void kernel_launch(void* const* d_in, const int* in_sizes, int n_in,
                              void* d_out, int out_size, void* d_ws, size_t ws_size,
                              hipStream_t stream) {
    const float* x    = (const float*)d_in[0];
    const float* W    = (const float*)d_in[1];
    const float* bias = (const float*)d_in[2];
    const float* eta  = (const float*)d_in[3];
    const int*   src  = (const int*)d_in[4];
    const int*   dst  = (const int*)d_in[5];
    float* out = (float*)d_out;

    const int  C   = in_sizes[2];          // 512
    const int  C3  = 3 * C;                // 1536
    const int  D   = in_sizes[1] / C3;     // 512
    const long xcount = in_sizes[0];       // N*D
    const int  N   = (int)(xcount / D);    // 100000
    const int  E   = in_sizes[4];          // 100000

    // workspace layout (16B-aligned): x_h | Wt | H | deg | cursor | off | eidx | bsum
    char* ws = (char*)d_ws;
    size_t o = 0;
    half_t* x_h  = (half_t*)(ws + o); o += (size_t)N * D * sizeof(half_t);
    half_t* Wt_h = (half_t*)(ws + o); o += (size_t)C3 * D * sizeof(half_t);
    half_t* H    = (half_t*)(ws + o); o += (size_t)N * C3 * sizeof(half_t);
    int* deg     = (int*)(ws + o);    o += (size_t)N * sizeof(int);
    int* cursor  = (int*)(ws + o);    o += (size_t)N * sizeof(int);
    int* off     = (int*)(ws + o);    o += (size_t)N * sizeof(int);
    int* eidx    = (int*)(ws + o);    o += (size_t)E * sizeof(int);
    int* bsum    = (int*)(ws + o);

    const int nb = (N + 1023) / 1024;      // scan chunks

    // 0. zero deg + cursor (adjacent)
    hipMemsetAsync(deg, 0, 2 * (size_t)N * sizeof(int), stream);
    // 1. x -> fp16
    cvt_x_kernel<<<(unsigned)((xcount / 8 + 255) / 256), 256, 0, stream>>>(x, x_h, xcount);
    // 2. W -> fp16 transposed
    cvt_w_kernel<<<(D * C3 + 255) / 256, 256, 0, stream>>>(W, Wt_h, D, C3);
    // 3. counting sort of edges by dst
    hist_kernel<<<(E + 255) / 256, 256, 0, stream>>>(dst, deg, E);
    scan_partial_kernel<<<nb, 256, 0, stream>>>(deg, bsum, N);
    scan_bsums_kernel<<<1, 1, 0, stream>>>(bsum, nb);
    scan_final_kernel<<<nb, 256, 0, stream>>>(deg, bsum, off, N);
    scatter_kernel<<<(E + 255) / 256, 256, 0, stream>>>(dst, off, cursor, eidx, E);
    // 4. GEMM h = x @ W
    {
        dim3 grid(C3 / BN, (N + BM - 1) / BM);
        gemm_kernel<<<grid, 256, 0, stream>>>(x_h, Wt_h, H, N, D, C3);
    }
    // 5. per-node aggregation, fused bias + tanh (no atomics, no memset of out)
    agg_kernel<<<(N + 3) / 4, 256, 0, stream>>>(H, eta, src, off, deg, eidx, bias, out, N, C, C3);
}

// Round 3
// 679.657 us; speedup vs baseline: 1.4873x; 1.0626x over previous
//
#include <hip/hip_runtime.h>

typedef _Float16 half_t;
typedef __attribute__((ext_vector_type(8))) _Float16 half8;
typedef __attribute__((ext_vector_type(4))) float floatx4;

#define BM 128
#define BN 128
#define BK 32

// ---------------- conversion + rearrange: W[d][s*C+c] -> Wt[c][s*D+d] fp16 ----------------
// GEMM B-operand: Bt[c][k] with k = s*512 + d, matching Z's [3][D] inner layout.
__global__ void cvt_w_kernel(const float* __restrict__ W, half_t* __restrict__ Wt,
                             int D, int C, int total) {
    int idx = blockIdx.x * blockDim.x + threadIdx.x;  // idx = c*1536 + s*512 + d
    if (idx >= total) return;
    int c = idx / 1536;
    int r = idx - c * 1536;           // s*512 + d
    int s = r >> 9;
    int d = r & 511;
    Wt[idx] = (half_t)W[(long)d * 1536 + s * 512 + c];  // W is 3 MB -> L2-resident
}

// ---------------- counting sort of edges by dst ----------------
__global__ void hist_kernel(const int* __restrict__ dst, int* __restrict__ deg, int E) {
    int e = blockIdx.x * blockDim.x + threadIdx.x;
    if (e < E) atomicAdd(&deg[dst[e]], 1);
}

__global__ void scan_partial_kernel(const int* __restrict__ deg, int* __restrict__ bsum, int n) {
    __shared__ int wsum[4];
    int t = threadIdx.x, lane = t & 63, w = t >> 6;
    int base = blockIdx.x * 1024 + t * 4;
    int s = 0;
#pragma unroll
    for (int j = 0; j < 4; ++j) { int i = base + j; if (i < n) s += deg[i]; }
#pragma unroll
    for (int o = 1; o < 64; o <<= 1) s += __shfl_xor(s, o);
    if (lane == 0) wsum[w] = s;
    __syncthreads();
    if (t == 0) bsum[blockIdx.x] = wsum[0] + wsum[1] + wsum[2] + wsum[3];
}

__global__ void scan_bsums_kernel(int* __restrict__ bsum, int nb) {
    int acc = 0;
    for (int i = 0; i < nb; ++i) { int v = bsum[i]; bsum[i] = acc; acc += v; }
}

__global__ void scan_final_kernel(const int* __restrict__ deg, const int* __restrict__ bsum,
                                  int* __restrict__ off, int n) {
    __shared__ int wsum[4];
    int t = threadIdx.x, lane = t & 63, w = t >> 6;
    int base = blockIdx.x * 1024 + t * 4;
    int v[4]; int s = 0;
#pragma unroll
    for (int j = 0; j < 4; ++j) { int i = base + j; v[j] = (i < n) ? deg[i] : 0; s += v[j]; }
    int sc = s;
#pragma unroll
    for (int o = 1; o < 64; o <<= 1) { int u = __shfl_up(sc, o); if (lane >= o) sc += u; }
    if (lane == 63) wsum[w] = sc;
    __syncthreads();
    int woff = 0;
    for (int i = 0; i < w; ++i) woff += wsum[i];
    int ex = bsum[blockIdx.x] + woff + (sc - s);
#pragma unroll
    for (int j = 0; j < 4; ++j) { int i = base + j; if (i < n) off[i] = ex; ex += v[j]; }
}

__global__ void scatter_kernel(const int* __restrict__ dst, const int* __restrict__ off,
                               int* __restrict__ cursor, int* __restrict__ eidx, int E) {
    int e = blockIdx.x * blockDim.x + threadIdx.x;
    if (e >= E) return;
    int d = dst[e];
    int p = off[d] + atomicAdd(&cursor[d], 1);
    eidx[p] = e;
}

// ---------------- pre-aggregation on x: Z[n,s,d] = sum_{e:dst=n} eta[e,s]*x[src_e,d] ----------------
// one wave per node; x (205 MB fp32) is L3-resident -> high-BW gather; Z written fp16.
__global__ __launch_bounds__(256) void aggx_kernel(
    const float* __restrict__ x, const float* __restrict__ eta,
    const int* __restrict__ src, const int* __restrict__ off,
    const int* __restrict__ deg, const int* __restrict__ eidx,
    half_t* __restrict__ Z, int N, int D)
{
    int node = blockIdx.x * 4 + (threadIdx.x >> 6);
    if (node >= N) return;
    int lane = threadIdx.x & 63;

    float a0[8] = {}, a1[8] = {}, a2[8] = {};
    int start = off[node];
    int d = deg[node];
    for (int q = 0; q < d; ++q) {
        int e = eidx[start + q];
        int s = src[e];
        float e0 = eta[3 * e + 0], e1 = eta[3 * e + 1], e2 = eta[3 * e + 2];
        const float* xr = x + (long)s * D + lane * 8;
        floatx4 v0 = *(const floatx4*)xr;
        floatx4 v1 = *(const floatx4*)(xr + 4);
#pragma unroll
        for (int j = 0; j < 4; ++j) {
            a0[j] += e0 * v0[j]; a0[j + 4] += e0 * v1[j];
            a1[j] += e1 * v0[j]; a1[j + 4] += e1 * v1[j];
            a2[j] += e2 * v0[j]; a2[j + 4] += e2 * v1[j];
        }
    }
    half_t* zr = Z + (long)node * (3 * D) + lane * 8;
    half8 h0, h1, h2;
#pragma unroll
    for (int j = 0; j < 8; ++j) { h0[j] = (half_t)a0[j]; h1[j] = (half_t)a1[j]; h2[j] = (half_t)a2[j]; }
    *(half8*)zr = h0;
    *(half8*)(zr + D) = h1;
    *(half8*)(zr + 2 * D) = h2;
}

// ---------------- GEMM + bias + tanh: out[M][C] = tanh(Z[M][K] @ Wt[C][K]^T + bias) ----------------
// m97-style with k-octet XOR swizzle (source-side, global_load_lds-compatible).
__global__ __launch_bounds__(256) void gemm_tanh_kernel(
    const half_t* __restrict__ A,    // Z: [M][K], K=1536
    const half_t* __restrict__ Bt,   // Wt: [C][K]
    const float* __restrict__ bias,  // [C]
    float* __restrict__ out,         // [M][C]
    int M, int K, int C)
{
    __shared__ half_t As[BM * BK];
    __shared__ half_t Bs[BN * BK];

    const int t    = threadIdx.x;
    const int lane = t & 63;
    const int wave = t >> 6;
    const int wm   = (wave >> 1) * 64;
    const int wn   = (wave & 1) * 64;
    const int m0   = blockIdx.y * BM;
    const int n0   = blockIdx.x * BN;

    // staging: thread t stages row r=t>>2 (and r+64), LDS slot t&3 (dest fixed: t*16B).
    // source octet swizzled: o_g = (t&3) ^ f(r), f(r)=(r>>1)&3 = (t>>3)&3 (same for r+64).
    const int r1 = t >> 2;
    const int r2 = r1 + 64;
    const int k8 = (((t & 3) ^ ((t >> 3) & 3))) * 8;
    const long gA1 = (long)min(m0 + r1, M - 1) * K + k8;
    const long gA2 = (long)min(m0 + r2, M - 1) * K + k8;
    const long gB1 = (long)(n0 + r1) * K + k8;
    const long gB2 = (long)(n0 + r2) * K + k8;

    floatx4 acc[4][4] = {};

    const int mrow = wm + (lane & 15);
    const int nrow = wn + (lane & 15);
    // fragment k-octet = lane>>4; row&... f(row) = (lane>>1)&3 (wm/wn,i*16 don't touch bits 1-2)
    const int koff = (((lane >> 4) ^ ((lane >> 1) & 3))) * 8;

    for (int kt = 0; kt < K; kt += BK) {
        __builtin_amdgcn_global_load_lds(
            (const __attribute__((address_space(1))) void*)(A + gA1 + kt),
            (__attribute__((address_space(3))) void*)(As + t * 8), 16, 0, 0);
        __builtin_amdgcn_global_load_lds(
            (const __attribute__((address_space(1))) void*)(A + gA2 + kt),
            (__attribute__((address_space(3))) void*)(As + (t + 256) * 8), 16, 0, 0);
        __builtin_amdgcn_global_load_lds(
            (const __attribute__((address_space(1))) void*)(Bt + gB1 + kt),
            (__attribute__((address_space(3))) void*)(Bs + t * 8), 16, 0, 0);
        __builtin_amdgcn_global_load_lds(
            (const __attribute__((address_space(1))) void*)(Bt + gB2 + kt),
            (__attribute__((address_space(3))) void*)(Bs + (t + 256) * 8), 16, 0, 0);
        __syncthreads();

        half8 af[4], bf[4];
#pragma unroll
        for (int i = 0; i < 4; ++i)
            af[i] = *(const half8*)&As[(mrow + i * 16) * BK + koff];
#pragma unroll
        for (int i = 0; i < 4; ++i)
            bf[i] = *(const half8*)&Bs[(nrow + i * 16) * BK + koff];
#pragma unroll
        for (int i = 0; i < 4; ++i)
#pragma unroll
            for (int j = 0; j < 4; ++j)
                acc[i][j] = __builtin_amdgcn_mfma_f32_16x16x32_f16(af[i], bf[j], acc[i][j], 0, 0, 0);
        __syncthreads();
    }

    // epilogue: D[m][n]: col = lane&15, row = (lane>>4)*4 + reg; fused bias + tanh
    const int col0 = lane & 15;
    const int rbase = (lane >> 4) * 4;
    float bj[4];
#pragma unroll
    for (int j = 0; j < 4; ++j)
        bj[j] = bias[n0 + wn + col0 + j * 16];
#pragma unroll
    for (int i = 0; i < 4; ++i) {
#pragma unroll
        for (int r = 0; r < 4; ++r) {
            int row = m0 + wm + i * 16 + rbase + r;
            if (row >= M) continue;
            long base = (long)row * C + n0 + wn + col0;
#pragma unroll
            for (int j = 0; j < 4; ++j) {
                float xv = acc[i][j][r] + bj[j];
                float ex = __expf(2.0f * xv);
                out[base + j * 16] = 1.0f - 2.0f / (ex + 1.0f);
            }
        }
    }
}

extern "C" void kernel_launch(void* const* d_in, const int* in_sizes, int n_in,
                              void* d_out, int out_size, void* d_ws, size_t ws_size,
                              hipStream_t stream) {
    const float* x    = (const float*)d_in[0];
    const float* W    = (const float*)d_in[1];
    const float* bias = (const float*)d_in[2];
    const float* eta  = (const float*)d_in[3];
    const int*   src  = (const int*)d_in[4];
    const int*   dst  = (const int*)d_in[5];
    float* out = (float*)d_out;

    const int  C   = in_sizes[2];          // 512
    const int  C3  = 3 * C;                // 1536
    const int  D   = in_sizes[1] / C3;     // 512
    const long xcount = in_sizes[0];       // N*D
    const int  N   = (int)(xcount / D);    // 100000
    const int  E   = in_sizes[4];          // 100000
    const int  K   = 3 * D;                // 1536 (GEMM inner dim)

    // workspace layout (16B-aligned): Z | Wt | deg | cursor | off | eidx | bsum
    char* ws = (char*)d_ws;
    size_t o = 0;
    half_t* Z    = (half_t*)(ws + o); o += (size_t)N * K * sizeof(half_t);
    half_t* Wt_h = (half_t*)(ws + o); o += (size_t)C * K * sizeof(half_t);
    int* deg     = (int*)(ws + o);    o += (size_t)N * sizeof(int);
    int* cursor  = (int*)(ws + o);    o += (size_t)N * sizeof(int);
    int* off     = (int*)(ws + o);    o += (size_t)N * sizeof(int);
    int* eidx    = (int*)(ws + o);    o += (size_t)E * sizeof(int);
    int* bsum    = (int*)(ws + o);

    const int nb = (N + 1023) / 1024;

    // 0. zero deg + cursor (adjacent)
    hipMemsetAsync(deg, 0, 2 * (size_t)N * sizeof(int), stream);
    // 1. W -> fp16, rearranged to [C][3*D]
    cvt_w_kernel<<<(C * K + 255) / 256, 256, 0, stream>>>(W, Wt_h, D, C, C * K);
    // 2. counting sort of edges by dst
    hist_kernel<<<(E + 255) / 256, 256, 0, stream>>>(dst, deg, E);
    scan_partial_kernel<<<nb, 256, 0, stream>>>(deg, bsum, N);
    scan_bsums_kernel<<<1, 1, 0, stream>>>(bsum, nb);
    scan_final_kernel<<<nb, 256, 0, stream>>>(deg, bsum, off, N);
    scatter_kernel<<<(E + 255) / 256, 256, 0, stream>>>(dst, off, cursor, eidx, E);
    // 3. pre-aggregation on x -> Z (fp16)
    aggx_kernel<<<(N + 3) / 4, 256, 0, stream>>>(x, eta, src, off, deg, eidx, Z, N, D);
    // 4. fused GEMM + bias + tanh -> out
    {
        dim3 grid(C / BN, (N + BM - 1) / BM);
        gemm_tanh_kernel<<<grid, 256, 0, stream>>>(Z, Wt_h, bias, out, N, K, C);
    }
}